// Round 10
// baseline (267.314 us; speedup 1.0000x reference)
//
#include <hip/hip_runtime.h>

// CrossScaleAttention: out = softmax(l2n(Q) l2n(K)^T * 32^-0.5) V
// B=4, Nq=Nk=4096, D=256, fp32 in/out.
// |scores| <= 0.1768 => no online max: O += exp(S) V, l += rowsum, divide at end.
// R17: R16 (best: 171.5us total, attn 90.0) + combine FUSED into attn's tail via
//   last-block reduction: the two ks-blocks of each (b,qt) group write
//   Opart/lpart, threadfence+atomicAdd a per-group counter (zeroed in prep;
//   kernel-boundary release makes it visible); second finisher acquires
//   (threadfence = L2 inv) and runs combine's exact math for its 64 rows.
//   Deletes the 3rd kernel launch + gap. Numerics identical to combine.
//   attn loop + prep otherwise R16 verbatim (Q-stride pad kept: conflicts
//   917K->131K confirmed).

#define NQ 4096
#define DIM 256
#define NROWS 16384      // B*NQ
#define BM 64            // q rows per workgroup
#define BN 64            // keys per iteration
#define KSPLIT 2
#define NITER 32         // (4096/KSPLIT)/BN
#define PSTRIDE 68       // Plds row stride (ushorts): 64 + 4 pad
#define QSTRIDE 264      // Q staging row stride (ushorts): 256 + 8 pad (R16)

typedef __attribute__((ext_vector_type(8))) short bf16x8;
typedef __attribute__((ext_vector_type(4))) float f32x4;
typedef __attribute__((ext_vector_type(16))) float f32x16;

__device__ __forceinline__ unsigned short f2bf(float f) {
  unsigned int u = __float_as_uint(f);
  u += 0x7fffu + ((u >> 16) & 1u);            // RNE
  return (unsigned short)(u >> 16);
}

__device__ __forceinline__ float bf2f(unsigned short h) {
  return __uint_as_float((unsigned int)h << 16);
}

// pack two positive floats to bf16 pair (round half up; ties-only deviation from RNE)
__device__ __forceinline__ unsigned int pack2bf(float a, float b) {
  unsigned int ua = __float_as_uint(a) + 0x8000u;
  unsigned int ub = __float_as_uint(b) + 0x8000u;
  return __builtin_amdgcn_perm(ub, ua, 0x07060302u);  // [ua.hi16 | ub.hi16]
}

__device__ __forceinline__ void gload16(const void* g, void* l) {
  __builtin_amdgcn_global_load_lds(
      (const __attribute__((address_space(1))) unsigned int*)g,
      (__attribute__((address_space(3))) unsigned int*)l, 16, 0, 0);
}

// ---------------------------------------------------------------------------
// prep (K/V only, balanced blocks). blk 0 additionally zeroes the 256 group
// counters (visible to attn via kernel-boundary release).
// ---------------------------------------------------------------------------
__global__ __launch_bounds__(256) void prep(
    const float* __restrict__ K, const float* __restrict__ V,
    unsigned short* __restrict__ Kfm, unsigned short* __restrict__ Vfm,
    int* __restrict__ cnt)
{
  __shared__ unsigned short vt[32 * 264];
  const int blk = blockIdx.x, tid = threadIdx.x;
  const int wave = tid >> 6, lane = tid & 63;
  if (blk == 0) cnt[tid] = 0;          // 256 counters, one per (b,qt) group
  if (blk < 512) {
    const int kt2 = blk;              // 32-row unit
    const int kt = kt2 >> 1, h = kt2 & 1;
    #pragma unroll
    for (int i = 0; i < 8; i++) {
      const int r = wave*8 + i;       // 0..31 local row
      float4 v = *(const float4*)(K + ((size_t)kt2*32 + r) * DIM + lane * 4);
      float ss = v.x*v.x + v.y*v.y + v.z*v.z + v.w*v.w;
      #pragma unroll
      for (int off = 1; off < 64; off <<= 1) ss += __shfl_xor(ss, off, 64);
      float scale = 1.0f / fmaxf(sqrtf(ss), 1e-12f);
      ushort4 o;
      o.x = f2bf(v.x*scale); o.y = f2bf(v.y*scale);
      o.z = f2bf(v.z*scale); o.w = f2bf(v.w*scale);
      *(ushort4*)(vt + r*264 + lane*4) = o;
    }
    __syncthreads();
    #pragma unroll
    for (int s = 0; s < 4; s++) {
      const int ch = tid + 256*s;          // 1024 chunks of 8 ushorts
      const int c = ch >> 5, r = ch & 31;
      const int n = h*32 + r;
      bf16x8 val = *(const bf16x8*)(vt + r*264 + c*8);
      *(bf16x8*)(Kfm + (size_t)kt*16384 + (size_t)(c*64 + n)*8) = val;
    }
  } else {
    const int NS = blk - 512;
    #pragma unroll
    for (int i = 0; i < 4; i++) {
      const int e = tid + 256*i;
      const int nl = e >> 6, d = (e & 63) * 4;
      float4 v = *(const float4*)(V + ((size_t)NS*16 + nl)*DIM + d);
      ushort4 o;
      o.x = f2bf(v.x); o.y = f2bf(v.y); o.z = f2bf(v.z); o.w = f2bf(v.w);
      *(ushort4*)(vt + nl*264 + d) = o;
    }
    __syncthreads();
    #pragma unroll
    for (int i = 0; i < 2; i++) {
      const int ch = tid + 256*i;
      const int db = ch >> 6, ln = ch & 63;
      const int row0 = (ln >> 5) * 8, dd = db*32 + (ln & 31);
      ushort4 a, b;
      a.x = vt[(row0+0)*264 + dd]; a.y = vt[(row0+1)*264 + dd];
      a.z = vt[(row0+2)*264 + dd]; a.w = vt[(row0+3)*264 + dd];
      b.x = vt[(row0+4)*264 + dd]; b.y = vt[(row0+5)*264 + dd];
      b.z = vt[(row0+6)*264 + dd]; b.w = vt[(row0+7)*264 + dd];
      size_t base = ((size_t)(NS*8 + db)*64 + ln)*8;
      *(ushort4*)(Vfm + base)     = a;
      *(ushort4*)(Vfm + base + 4) = b;
    }
  }
}

// ---------------------------------------------------------------------------
// attn: grid=512, 256 thr (4 waves), 2 blocks/CU. R16 loop verbatim.
// Tail: last-block-per-(b,qt) fused combine (device-scope counter + fences).
// ---------------------------------------------------------------------------
__global__ __launch_bounds__(256, 2) void attn(
    const float* __restrict__ Qg,
    const unsigned short* __restrict__ Kfm,
    const unsigned short* __restrict__ Vfm,
    unsigned short* __restrict__ Opart, float* __restrict__ lpart,
    int* __restrict__ cnt, float* __restrict__ out)
{
  __shared__ unsigned short Klds[2][32 * 64 * 8];  // 2 x 32 KB chunk-major (bufs also Q staging)
  __shared__ unsigned short Plds[BM * PSTRIDE];    // 8704 B row-major padded
  __shared__ int last_s;

  const int tid = threadIdx.x, wave = tid >> 6, lane = tid & 63;
  const int l15 = lane & 15, l4 = lane >> 4;
  const int blk = blockIdx.x;
  const int g = blk & 7, qt = blk >> 3;
  const int b = g >> 1, ks = g & 1;
  const int Rq0 = b*NQ + qt*BM;
  const int n0base = b*NQ + ks*(NQ/KSPLIT);
  const int mi = wave & 1, ni = wave >> 1;

  // ---- prologue: normalize 64 Q rows into padded staging (stride 264) ----
  {
    unsigned short* Qlds = &Klds[0][0];
    #pragma unroll
    for (int i = 0; i < 16; i++) {
      const int r = wave*16 + i;
      float4 v = *(const float4*)(Qg + (size_t)(Rq0 + r)*DIM + lane*4);
      float ss = v.x*v.x + v.y*v.y + v.z*v.z + v.w*v.w;
      #pragma unroll
      for (int off = 1; off < 64; off <<= 1) ss += __shfl_xor(ss, off, 64);
      float scale = (0.17677669529663687f * 1.4426950408889634f)   // SCALE*log2e
                    / fmaxf(sqrtf(ss), 1e-12f);
      ushort4 o;
      o.x = f2bf(v.x*scale); o.y = f2bf(v.y*scale);
      o.z = f2bf(v.z*scale); o.w = f2bf(v.w*scale);
      *(ushort4*)(Qlds + r*QSTRIDE + lane*4) = o;   // spans into buf1 (safe pre-stage)
    }
  }
  __syncthreads();

  // Q B-frags: local row = mi*32 + mt*16 + l15, k = kg*32 + l4*8 (stride 264 -> 2-way, free)
  bf16x8 qf[2][8];
  #pragma unroll
  for (int mt = 0; mt < 2; mt++) {
    const unsigned short* qrow = &Klds[0][0] + (mi*32 + mt*16 + l15)*QSTRIDE + l4*8;
    #pragma unroll
    for (int kg = 0; kg < 8; kg++)
      qf[mt][kg] = *(const bf16x8*)(qrow + kg*32);
  }
  __syncthreads();   // all Q reads done before stage(0)/stage(1) overwrite bufs

  f32x16 oacc[2][2] = {};   // [mt2][dt]
  float lacc[2] = {};       // [mt]

  auto stage = [&](int kt_) {
    unsigned short* dst = &Klds[kt_ & 1][0];
    const unsigned short* src = Kfm + (size_t)((n0base + kt_*BN) >> 6) * (32*64*8);
    #pragma unroll
    for (int jj = 0; jj < 4; jj++) {
      const int c = wave*8 + jj*2;      // 8 chunks (1 KB each) per wave
      gload16(src + (size_t)c*512 + lane*8,     dst + (size_t)c*512);
      gload16(src + (size_t)(c+1)*512 + lane*8, dst + (size_t)(c+1)*512);
    }
  };

  stage(0);

  for (int kt = 0; kt < NITER; kt++) {
    __syncthreads();   // stage(kt) drained; prev P fully consumed

    if (kt + 1 < NITER) stage(kt + 1);   // retires under S+P via in-order vmcnt
    __builtin_amdgcn_sched_barrier(0);   // keep stage issue ahead of S phase

    const unsigned short* kb = &Klds[kt & 1][0];

    // ---- S^T = Khat Qhat^T (scale folded into Q) ----
    f32x4 sacc[2][2] = {};   // [nt][mt]
    #pragma unroll
    for (int kg = 0; kg < 8; kg++) {
      bf16x8 kf[2];
      #pragma unroll
      for (int nt = 0; nt < 2; nt++) {
        const int nrow = ni*32 + nt*16 + l15;
        const int c = kg*4 + l4;
        kf[nt] = *(const bf16x8*)(kb + ((size_t)(c*64 + nrow))*8);
      }
      __builtin_amdgcn_s_setprio(1);
      #pragma unroll
      for (int nt = 0; nt < 2; nt++)
        #pragma unroll
        for (int mt = 0; mt < 2; mt++)
          sacc[nt][mt] = __builtin_amdgcn_mfma_f32_16x16x32_bf16(
              kf[nt], qf[mt][kg], sacc[nt][mt], 0, 0, 0);
      __builtin_amdgcn_s_setprio(0);
    }

    // ---- P = exp2(S); row-sums; packed b64 writes to Plds[m][n] ----
    #pragma unroll
    for (int nt = 0; nt < 2; nt++)
      #pragma unroll
      for (int mt = 0; mt < 2; mt++) {
        float p0 = __builtin_amdgcn_exp2f(sacc[nt][mt][0]);
        float p1 = __builtin_amdgcn_exp2f(sacc[nt][mt][1]);
        float p2 = __builtin_amdgcn_exp2f(sacc[nt][mt][2]);
        float p3 = __builtin_amdgcn_exp2f(sacc[nt][mt][3]);
        lacc[mt] += (p0 + p1) + (p2 + p3);
        uint2 pk;
        pk.x = pack2bf(p0, p1);
        pk.y = pack2bf(p2, p3);
        const int m = mi*32 + mt*16 + l15;
        const int n = ni*32 + nt*16 + 4*l4;
        *(uint2*)(Plds + m*PSTRIDE + n) = pk;
      }

    // mid barrier: P visible (lgkm only) -- stage(kt+1) stays in flight.
    asm volatile("s_waitcnt lgkmcnt(0)" ::: "memory");
    __builtin_amdgcn_s_barrier();
    __builtin_amdgcn_sched_barrier(0);

    // ---- O += P V (depth-1 pipelined pf/vf) ----
    const int NB0 = (n0base + kt*BN) >> 4;
    bf16x8 pf[2][2], vf[2][2];
    #pragma unroll
    for (int mt2 = 0; mt2 < 2; mt2++)
      pf[0][mt2] = *(const bf16x8*)(Plds + (mt2*32 + (lane & 31))*PSTRIDE
                                    + 8*(lane >> 5));
    #pragma unroll
    for (int dt = 0; dt < 2; dt++)
      vf[0][dt] = *(const bf16x8*)(Vfm + ((size_t)(NB0*8 + wave*2 + dt)*64 + lane)*8);
    #pragma unroll
    for (int kstep = 0; kstep < 4; kstep++) {
      const int cb = kstep & 1;
      if (kstep < 3) {
        #pragma unroll
        for (int mt2 = 0; mt2 < 2; mt2++)
          pf[cb^1][mt2] = *(const bf16x8*)(Plds + (mt2*32 + (lane & 31))*PSTRIDE
                                           + (kstep+1)*16 + 8*(lane >> 5));
        #pragma unroll
        for (int dt = 0; dt < 2; dt++)
          vf[cb^1][dt] = *(const bf16x8*)(Vfm
              + ((size_t)((NB0 + kstep + 1)*8 + wave*2 + dt)*64 + lane)*8);
      }
      __builtin_amdgcn_s_setprio(1);
      #pragma unroll
      for (int mt2 = 0; mt2 < 2; mt2++)
        #pragma unroll
        for (int dt = 0; dt < 2; dt++)
          oacc[mt2][dt] = __builtin_amdgcn_mfma_f32_32x32x16_bf16(
              pf[cb][mt2], vf[cb][dt], oacc[mt2][dt], 0, 0, 0);
      __builtin_amdgcn_s_setprio(0);
    }
  }

  // ---- epilogue: l row-sums (reduce over l4 groups) ----
  #pragma unroll
  for (int mt = 0; mt < 2; mt++) {
    float s = lacc[mt];
    s += __shfl_xor(s, 16, 64);
    s += __shfl_xor(s, 32, 64);
    if (l4 == 0)
      lpart[(size_t)(ks*2 + ni)*NROWS + Rq0 + mi*32 + mt*16 + l15] = s;
  }

  // ---- epilogue: O stores (bf16) ----
  #pragma unroll
  for (int mt2 = 0; mt2 < 2; mt2++)
    #pragma unroll
    for (int dt = 0; dt < 2; dt++)
      #pragma unroll
      for (int reg = 0; reg < 16; reg++) {
        const int m = mt2*32 + 4*(lane >> 5) + (reg & 3) + 8*(reg >> 2);
        const int d = wave*64 + dt*32 + (lane & 31);
        Opart[((size_t)(ks*NROWS + Rq0 + m))*DIM + d] = f2bf(oacc[mt2][dt][reg]);
      }

  // ---- fused combine: last block of the (b,qt) pair divides & writes out ----
  __threadfence();                      // release: Opart/lpart -> device scope
  __syncthreads();                      // all threads' stores fenced
  if (tid == 0)
    last_s = atomicAdd(&cnt[(g >> 1)*64 + qt], 1);   // device-scope
  __syncthreads();
  if (last_s == 1) {
    __threadfence();                    // acquire: invalidate stale L1/L2
    #pragma unroll
    for (int i = 0; i < 16; i++) {
      const int e4 = tid + 256*i;                      // 0..4095 float4s
      const size_t e = (size_t)Rq0*DIM + (size_t)e4*4;
      const int R = Rq0 + (e4 >> 6);
      float ls = lpart[R] + lpart[NROWS + R]
               + lpart[2*NROWS + R] + lpart[3*NROWS + R];
      float inv = 1.0f / ls;
      ushort4 o0 = *(const ushort4*)(Opart + e);
      ushort4 o1 = *(const ushort4*)(Opart + (size_t)NROWS*DIM + e);
      float4 o;
      o.x = (bf2f(o0.x) + bf2f(o1.x))*inv;
      o.y = (bf2f(o0.y) + bf2f(o1.y))*inv;
      o.z = (bf2f(o0.z) + bf2f(o1.z))*inv;
      o.w = (bf2f(o0.w) + bf2f(o1.w))*inv;
      *(float4*)(out + e) = o;
    }
  }
}

extern "C" void kernel_launch(void* const* d_in, const int* in_sizes, int n_in,
                              void* d_out, int out_size, void* d_ws, size_t ws_size,
                              hipStream_t stream) {
  const float* Q = (const float*)d_in[0];
  const float* K = (const float*)d_in[1];
  const float* V = (const float*)d_in[2];
  char* ws = (char*)d_ws;
  // ws layout: Kfm 8 MiB | Vfm 8 MiB | Opart(bf16) 16 MiB | lpart 256 KiB | cnt 1 KiB
  unsigned short* Kfm   = (unsigned short*)(ws);
  unsigned short* Vfm   = (unsigned short*)(ws + 8388608);
  unsigned short* Opart = (unsigned short*)(ws + 16777216);
  float* lpart = (float*)(ws + 33554432);
  int* cnt     = (int*)(ws + 33554432 + 262144);

  prep<<<1536, 256, 0, stream>>>(K, V, Kfm, Vfm, cnt);
  attn<<<512, 256, 0, stream>>>(Q, Kfm, Vfm, Opart, lpart, cnt, (float*)d_out);
}

// Round 11
// 172.446 us; speedup vs baseline: 1.5501x; 1.5501x over previous
//
#include <hip/hip_runtime.h>

// CrossScaleAttention: out = softmax(l2n(Q) l2n(K)^T * 32^-0.5) V
// B=4, Nq=Nk=4096, D=256, fp32 in/out.
// |scores| <= 0.1768 => no online max: O += exp(S) V, l += rowsum, divide at end.
// R18 == R16 (session best, 171.5us; prediction-matched). R17's fused-combine
//   fences cost ~105us of L2 writeback/invalidate traffic -> reverted.
//   Final structure: prep (K/V normalize+pack) -> attn (dbuf Klds, stage-at-top,
//   lgkm-only mid barrier, padded Q staging) -> combine.

#define NQ 4096
#define DIM 256
#define NROWS 16384      // B*NQ
#define BM 64            // q rows per workgroup
#define BN 64            // keys per iteration
#define KSPLIT 2
#define NITER 32         // (4096/KSPLIT)/BN
#define PSTRIDE 68       // Plds row stride (ushorts): 64 + 4 pad
#define QSTRIDE 264      // Q staging row stride (ushorts): 256 + 8 pad (R16)

typedef __attribute__((ext_vector_type(8))) short bf16x8;
typedef __attribute__((ext_vector_type(4))) float f32x4;
typedef __attribute__((ext_vector_type(16))) float f32x16;

__device__ __forceinline__ unsigned short f2bf(float f) {
  unsigned int u = __float_as_uint(f);
  u += 0x7fffu + ((u >> 16) & 1u);            // RNE
  return (unsigned short)(u >> 16);
}

__device__ __forceinline__ float bf2f(unsigned short h) {
  return __uint_as_float((unsigned int)h << 16);
}

// pack two positive floats to bf16 pair (round half up; ties-only deviation from RNE)
__device__ __forceinline__ unsigned int pack2bf(float a, float b) {
  unsigned int ua = __float_as_uint(a) + 0x8000u;
  unsigned int ub = __float_as_uint(b) + 0x8000u;
  return __builtin_amdgcn_perm(ub, ua, 0x07060302u);  // [ua.hi16 | ub.hi16]
}

__device__ __forceinline__ void gload16(const void* g, void* l) {
  __builtin_amdgcn_global_load_lds(
      (const __attribute__((address_space(1))) unsigned int*)g,
      (__attribute__((address_space(3))) unsigned int*)l, 16, 0, 0);
}

// ---------------------------------------------------------------------------
// prep (K/V only, balanced blocks):
//  [0,512):    K 32-row half-tiles -> normalize -> LDS -> chunk-major Kfm
//              [tile64][c:32][n:64][8], coalesced 512B store runs.
//  [512,1536): V 16-row tiles -> B-frag-major Vfm via LDS transpose.
// ---------------------------------------------------------------------------
__global__ __launch_bounds__(256) void prep(
    const float* __restrict__ K, const float* __restrict__ V,
    unsigned short* __restrict__ Kfm, unsigned short* __restrict__ Vfm)
{
  __shared__ unsigned short vt[32 * 264];
  const int blk = blockIdx.x, tid = threadIdx.x;
  const int wave = tid >> 6, lane = tid & 63;
  if (blk < 512) {
    const int kt2 = blk;              // 32-row unit
    const int kt = kt2 >> 1, h = kt2 & 1;
    #pragma unroll
    for (int i = 0; i < 8; i++) {
      const int r = wave*8 + i;       // 0..31 local row
      float4 v = *(const float4*)(K + ((size_t)kt2*32 + r) * DIM + lane * 4);
      float ss = v.x*v.x + v.y*v.y + v.z*v.z + v.w*v.w;
      #pragma unroll
      for (int off = 1; off < 64; off <<= 1) ss += __shfl_xor(ss, off, 64);
      float scale = 1.0f / fmaxf(sqrtf(ss), 1e-12f);
      ushort4 o;
      o.x = f2bf(v.x*scale); o.y = f2bf(v.y*scale);
      o.z = f2bf(v.z*scale); o.w = f2bf(v.w*scale);
      *(ushort4*)(vt + r*264 + lane*4) = o;
    }
    __syncthreads();
    #pragma unroll
    for (int s = 0; s < 4; s++) {
      const int ch = tid + 256*s;          // 1024 chunks of 8 ushorts
      const int c = ch >> 5, r = ch & 31;
      const int n = h*32 + r;
      bf16x8 val = *(const bf16x8*)(vt + r*264 + c*8);
      *(bf16x8*)(Kfm + (size_t)kt*16384 + (size_t)(c*64 + n)*8) = val;
    }
  } else {
    const int NS = blk - 512;
    #pragma unroll
    for (int i = 0; i < 4; i++) {
      const int e = tid + 256*i;
      const int nl = e >> 6, d = (e & 63) * 4;
      float4 v = *(const float4*)(V + ((size_t)NS*16 + nl)*DIM + d);
      ushort4 o;
      o.x = f2bf(v.x); o.y = f2bf(v.y); o.z = f2bf(v.z); o.w = f2bf(v.w);
      *(ushort4*)(vt + nl*264 + d) = o;
    }
    __syncthreads();
    #pragma unroll
    for (int i = 0; i < 2; i++) {
      const int ch = tid + 256*i;
      const int db = ch >> 6, ln = ch & 63;
      const int row0 = (ln >> 5) * 8, dd = db*32 + (ln & 31);
      ushort4 a, b;
      a.x = vt[(row0+0)*264 + dd]; a.y = vt[(row0+1)*264 + dd];
      a.z = vt[(row0+2)*264 + dd]; a.w = vt[(row0+3)*264 + dd];
      b.x = vt[(row0+4)*264 + dd]; b.y = vt[(row0+5)*264 + dd];
      b.z = vt[(row0+6)*264 + dd]; b.w = vt[(row0+7)*264 + dd];
      size_t base = ((size_t)(NS*8 + db)*64 + ln)*8;
      *(ushort4*)(Vfm + base)     = a;
      *(ushort4*)(Vfm + base + 4) = b;
    }
  }
}

// ---------------------------------------------------------------------------
// attn: grid=512, 256 thr (4 waves), 2 blocks/CU. blk&7 -> (b,ks) for L2
// locality. Double-buffered Klds; stage(kt+1) issued at TOP of iter kt (retires
// under S via in-order vmcnt); mid barrier is lgkm-only (stage stays in flight);
// O phase pf/vf depth-1 pipelined; setprio around MFMA clusters.
// Q staging stride 264 (bank conflicts 917K->131K, measured R16).
// ---------------------------------------------------------------------------
__global__ __launch_bounds__(256, 2) void attn(
    const float* __restrict__ Qg,
    const unsigned short* __restrict__ Kfm,
    const unsigned short* __restrict__ Vfm,
    unsigned short* __restrict__ Opart, float* __restrict__ lpart)
{
  __shared__ unsigned short Klds[2][32 * 64 * 8];  // 2 x 32 KB chunk-major (both bufs also Q staging)
  __shared__ unsigned short Plds[BM * PSTRIDE];    // 8704 B row-major padded

  const int tid = threadIdx.x, wave = tid >> 6, lane = tid & 63;
  const int l15 = lane & 15, l4 = lane >> 4;
  const int blk = blockIdx.x;
  const int g = blk & 7, qt = blk >> 3;
  const int b = g >> 1, ks = g & 1;
  const int Rq0 = b*NQ + qt*BM;
  const int n0base = b*NQ + ks*(NQ/KSPLIT);
  const int mi = wave & 1, ni = wave >> 1;

  // ---- prologue: normalize 64 Q rows into padded staging (stride 264) ----
  {
    unsigned short* Qlds = &Klds[0][0];
    #pragma unroll
    for (int i = 0; i < 16; i++) {
      const int r = wave*16 + i;
      float4 v = *(const float4*)(Qg + (size_t)(Rq0 + r)*DIM + lane*4);
      float ss = v.x*v.x + v.y*v.y + v.z*v.z + v.w*v.w;
      #pragma unroll
      for (int off = 1; off < 64; off <<= 1) ss += __shfl_xor(ss, off, 64);
      float scale = (0.17677669529663687f * 1.4426950408889634f)   // SCALE*log2e
                    / fmaxf(sqrtf(ss), 1e-12f);
      ushort4 o;
      o.x = f2bf(v.x*scale); o.y = f2bf(v.y*scale);
      o.z = f2bf(v.z*scale); o.w = f2bf(v.w*scale);
      *(ushort4*)(Qlds + r*QSTRIDE + lane*4) = o;   // spans into buf1 (safe pre-stage)
    }
  }
  __syncthreads();

  // Q B-frags: local row = mi*32 + mt*16 + l15, k = kg*32 + l4*8 (stride 264 -> 2-way, free)
  bf16x8 qf[2][8];
  #pragma unroll
  for (int mt = 0; mt < 2; mt++) {
    const unsigned short* qrow = &Klds[0][0] + (mi*32 + mt*16 + l15)*QSTRIDE + l4*8;
    #pragma unroll
    for (int kg = 0; kg < 8; kg++)
      qf[mt][kg] = *(const bf16x8*)(qrow + kg*32);
  }
  __syncthreads();   // all Q reads done before stage(0)/stage(1) overwrite bufs

  f32x16 oacc[2][2] = {};   // [mt2][dt]
  float lacc[2] = {};       // [mt]

  auto stage = [&](int kt_) {
    unsigned short* dst = &Klds[kt_ & 1][0];
    const unsigned short* src = Kfm + (size_t)((n0base + kt_*BN) >> 6) * (32*64*8);
    #pragma unroll
    for (int jj = 0; jj < 4; jj++) {
      const int c = wave*8 + jj*2;      // 8 chunks (1 KB each) per wave
      gload16(src + (size_t)c*512 + lane*8,     dst + (size_t)c*512);
      gload16(src + (size_t)(c+1)*512 + lane*8, dst + (size_t)(c+1)*512);
    }
  };

  stage(0);

  for (int kt = 0; kt < NITER; kt++) {
    __syncthreads();   // stage(kt) drained; prev P fully consumed

    if (kt + 1 < NITER) stage(kt + 1);   // retires under S+P via in-order vmcnt
    __builtin_amdgcn_sched_barrier(0);   // keep stage issue ahead of S phase

    const unsigned short* kb = &Klds[kt & 1][0];

    // ---- S^T = Khat Qhat^T (scale folded into Q) ----
    f32x4 sacc[2][2] = {};   // [nt][mt]
    #pragma unroll
    for (int kg = 0; kg < 8; kg++) {
      bf16x8 kf[2];
      #pragma unroll
      for (int nt = 0; nt < 2; nt++) {
        const int nrow = ni*32 + nt*16 + l15;
        const int c = kg*4 + l4;
        kf[nt] = *(const bf16x8*)(kb + ((size_t)(c*64 + nrow))*8);
      }
      __builtin_amdgcn_s_setprio(1);
      #pragma unroll
      for (int nt = 0; nt < 2; nt++)
        #pragma unroll
        for (int mt = 0; mt < 2; mt++)
          sacc[nt][mt] = __builtin_amdgcn_mfma_f32_16x16x32_bf16(
              kf[nt], qf[mt][kg], sacc[nt][mt], 0, 0, 0);
      __builtin_amdgcn_s_setprio(0);
    }

    // ---- P = exp2(S); row-sums; packed b64 writes to Plds[m][n] ----
    #pragma unroll
    for (int nt = 0; nt < 2; nt++)
      #pragma unroll
      for (int mt = 0; mt < 2; mt++) {
        float p0 = __builtin_amdgcn_exp2f(sacc[nt][mt][0]);
        float p1 = __builtin_amdgcn_exp2f(sacc[nt][mt][1]);
        float p2 = __builtin_amdgcn_exp2f(sacc[nt][mt][2]);
        float p3 = __builtin_amdgcn_exp2f(sacc[nt][mt][3]);
        lacc[mt] += (p0 + p1) + (p2 + p3);
        uint2 pk;
        pk.x = pack2bf(p0, p1);
        pk.y = pack2bf(p2, p3);
        const int m = mi*32 + mt*16 + l15;
        const int n = ni*32 + nt*16 + 4*l4;
        *(uint2*)(Plds + m*PSTRIDE + n) = pk;
      }

    // mid barrier: P visible (lgkm only) -- stage(kt+1) stays in flight.
    asm volatile("s_waitcnt lgkmcnt(0)" ::: "memory");
    __builtin_amdgcn_s_barrier();
    __builtin_amdgcn_sched_barrier(0);

    // ---- O += P V (depth-1 pipelined pf/vf) ----
    const int NB0 = (n0base + kt*BN) >> 4;
    bf16x8 pf[2][2], vf[2][2];
    #pragma unroll
    for (int mt2 = 0; mt2 < 2; mt2++)
      pf[0][mt2] = *(const bf16x8*)(Plds + (mt2*32 + (lane & 31))*PSTRIDE
                                    + 8*(lane >> 5));
    #pragma unroll
    for (int dt = 0; dt < 2; dt++)
      vf[0][dt] = *(const bf16x8*)(Vfm + ((size_t)(NB0*8 + wave*2 + dt)*64 + lane)*8);
    #pragma unroll
    for (int kstep = 0; kstep < 4; kstep++) {
      const int cb = kstep & 1;
      if (kstep < 3) {
        #pragma unroll
        for (int mt2 = 0; mt2 < 2; mt2++)
          pf[cb^1][mt2] = *(const bf16x8*)(Plds + (mt2*32 + (lane & 31))*PSTRIDE
                                           + (kstep+1)*16 + 8*(lane >> 5));
        #pragma unroll
        for (int dt = 0; dt < 2; dt++)
          vf[cb^1][dt] = *(const bf16x8*)(Vfm
              + ((size_t)((NB0 + kstep + 1)*8 + wave*2 + dt)*64 + lane)*8);
      }
      __builtin_amdgcn_s_setprio(1);
      #pragma unroll
      for (int mt2 = 0; mt2 < 2; mt2++)
        #pragma unroll
        for (int dt = 0; dt < 2; dt++)
          oacc[mt2][dt] = __builtin_amdgcn_mfma_f32_32x32x16_bf16(
              pf[cb][mt2], vf[cb][dt], oacc[mt2][dt], 0, 0, 0);
      __builtin_amdgcn_s_setprio(0);
    }
  }

  // ---- epilogue: l row-sums (reduce over l4 groups) ----
  #pragma unroll
  for (int mt = 0; mt < 2; mt++) {
    float s = lacc[mt];
    s += __shfl_xor(s, 16, 64);
    s += __shfl_xor(s, 32, 64);
    if (l4 == 0)
      lpart[(size_t)(ks*2 + ni)*NROWS + Rq0 + mi*32 + mt*16 + l15] = s;
  }

  // ---- epilogue: O stores (bf16) ----
  #pragma unroll
  for (int mt2 = 0; mt2 < 2; mt2++)
    #pragma unroll
    for (int dt = 0; dt < 2; dt++)
      #pragma unroll
      for (int reg = 0; reg < 16; reg++) {
        const int m = mt2*32 + 4*(lane >> 5) + (reg & 3) + 8*(reg >> 2);
        const int d = wave*64 + dt*32 + (lane & 31);
        Opart[((size_t)(ks*NROWS + Rq0 + m))*DIM + d] = f2bf(oacc[mt2][dt][reg]);
      }
}

// ---------------------------------------------------------------------------
// combine: out = (O0+O1) / (l0+l1+l2+l3), Opart in bf16
// ---------------------------------------------------------------------------
__global__ __launch_bounds__(256) void combine(
    const unsigned short* __restrict__ Opart, const float* __restrict__ lpart,
    float* __restrict__ out)
{
  const size_t idx = (size_t)blockIdx.x*256 + threadIdx.x;
  const size_t e = idx*4;
  const int R = (int)(e >> 8);
  ushort4 o0 = *(const ushort4*)(Opart + e);
  ushort4 o1 = *(const ushort4*)(Opart + (size_t)NROWS*DIM + e);
  float ls = lpart[R] + lpart[NROWS + R] + lpart[2*NROWS + R] + lpart[3*NROWS + R];
  float inv = 1.0f / ls;
  float4 o;
  o.x = (bf2f(o0.x) + bf2f(o1.x))*inv;
  o.y = (bf2f(o0.y) + bf2f(o1.y))*inv;
  o.z = (bf2f(o0.z) + bf2f(o1.z))*inv;
  o.w = (bf2f(o0.w) + bf2f(o1.w))*inv;
  *(float4*)(out + e) = o;
}

extern "C" void kernel_launch(void* const* d_in, const int* in_sizes, int n_in,
                              void* d_out, int out_size, void* d_ws, size_t ws_size,
                              hipStream_t stream) {
  const float* Q = (const float*)d_in[0];
  const float* K = (const float*)d_in[1];
  const float* V = (const float*)d_in[2];
  char* ws = (char*)d_ws;
  // ws layout: Kfm 8 MiB | Vfm 8 MiB | Opart(bf16) 16 MiB | lpart 256 KiB
  unsigned short* Kfm   = (unsigned short*)(ws);
  unsigned short* Vfm   = (unsigned short*)(ws + 8388608);
  unsigned short* Opart = (unsigned short*)(ws + 16777216);
  float* lpart = (float*)(ws + 33554432);

  prep<<<1536, 256, 0, stream>>>(K, V, Kfm, Vfm);
  attn<<<512, 256, 0, stream>>>(Q, Kfm, Vfm, Opart, lpart);
  combine<<<4096, 256, 0, stream>>>(Opart, lpart, (float*)d_out);
}